// Round 1
// baseline (274.663 us; speedup 1.0000x reference)
//
#include <hip/hip_runtime.h>

#define K 5
#define D 128
#define BLOCK 256
#define NBLOCKS 2048

// Insert (sim, idx) into a descending-sorted top-K list held in registers.
__device__ __forceinline__ void insert_top(float sim, int idx, float bv[K], int bi[K]) {
    if (sim > bv[K - 1]) {
        bv[K - 1] = sim;
        bi[K - 1] = idx;
#pragma unroll
        for (int j = K - 1; j > 0; --j) {
            if (bv[j] > bv[j - 1]) {
                float tv = bv[j]; bv[j] = bv[j - 1]; bv[j - 1] = tv;
                int   ti = bi[j]; bi[j] = bi[j - 1]; bi[j - 1] = ti;
            }
        }
    }
}

// Pass 1: each 32-lane group computes cosine sim for its rows (grid-stride),
// keeps a register top-K; block merges groups' lists -> 5 candidates/block.
extern "C" __global__ void __launch_bounds__(BLOCK)
cossim_topk_pass1(const float* __restrict__ q, const float* __restrict__ M, int N,
                  float* __restrict__ cand_v, int* __restrict__ cand_i) {
    const int tid  = threadIdx.x;
    const int l    = tid & 31;                 // lane within 32-group
    const int gpb  = blockDim.x >> 5;          // groups per block (8)
    const int gid  = blockIdx.x * gpb + (tid >> 5);
    const int ngrp = gridDim.x * gpb;

    // Each lane holds 4 consecutive q elements (32 lanes * 4 = 128 = D).
    const float4 qv = reinterpret_cast<const float4*>(q)[l];

    // ||q|| via butterfly reduce within the 32-lane group.
    float q2 = qv.x * qv.x + qv.y * qv.y + qv.z * qv.z + qv.w * qv.w;
#pragma unroll
    for (int m = 16; m >= 1; m >>= 1) q2 += __shfl_xor(q2, m);
    const float qn = sqrtf(q2);

    float bv[K]; int bi[K];
#pragma unroll
    for (int j = 0; j < K; ++j) { bv[j] = -3.0e38f; bi[j] = 0; }

    for (int row = gid; row < N; row += ngrp) {
        const float4 v = reinterpret_cast<const float4*>(M + (size_t)row * D)[l];
        float dot = fmaf(v.x, qv.x, fmaf(v.y, qv.y, fmaf(v.z, qv.z, v.w * qv.w)));
        float ss  = fmaf(v.x, v.x,  fmaf(v.y, v.y,  fmaf(v.z, v.z,  v.w * v.w)));
#pragma unroll
        for (int m = 16; m >= 1; m >>= 1) {
            dot += __shfl_xor(dot, m);
            ss  += __shfl_xor(ss, m);
        }
        const float sim = dot / fmaxf(qn * sqrtf(ss), 1e-8f);
        insert_top(sim, row, bv, bi);   // all 32 lanes maintain identical lists (no divergence)
    }

    // Merge the block's 8 group-lists.
    __shared__ float sv[(BLOCK / 32) * K];
    __shared__ int   si[(BLOCK / 32) * K];
    if (l == 0) {
        const int g = tid >> 5;
#pragma unroll
        for (int j = 0; j < K; ++j) { sv[g * K + j] = bv[j]; si[g * K + j] = bi[j]; }
    }
    __syncthreads();
    if (tid == 0) {
        float mv[K]; int mi[K];
#pragma unroll
        for (int j = 0; j < K; ++j) { mv[j] = sv[j]; mi[j] = si[j]; }
        for (int c = K; c < gpb * K; ++c) insert_top(sv[c], si[c], mv, mi);
#pragma unroll
        for (int j = 0; j < K; ++j) {
            cand_v[blockIdx.x * K + j] = mv[j];
            cand_i[blockIdx.x * K + j] = mi[j];
        }
    }
}

// Pass 2: one 64-thread block reduces NBLOCKS*K candidates to global top-K.
extern "C" __global__ void __launch_bounds__(64)
cossim_topk_pass2(const float* __restrict__ cand_v, const int* __restrict__ cand_i,
                  int ncand, float* __restrict__ out) {
    const int tid = threadIdx.x;
    float bv[K]; int bi[K];
#pragma unroll
    for (int j = 0; j < K; ++j) { bv[j] = -3.0e38f; bi[j] = 0; }

    for (int c = tid; c < ncand; c += 64) insert_top(cand_v[c], cand_i[c], bv, bi);

    __shared__ float sv[64 * K];
    __shared__ int   si[64 * K];
#pragma unroll
    for (int j = 0; j < K; ++j) { sv[tid * K + j] = bv[j]; si[tid * K + j] = bi[j]; }
    __syncthreads();

    if (tid == 0) {
        float mv[K]; int mi[K];
#pragma unroll
        for (int j = 0; j < K; ++j) { mv[j] = -3.0e38f; mi[j] = 0; }
        for (int c = 0; c < 64 * K; ++c) insert_top(sv[c], si[c], mv, mi);
        // Output layout: [top_vals (K floats)] [top_idx (K, written as float)]
#pragma unroll
        for (int j = 0; j < K; ++j) {
            out[j]     = mv[j];
            out[K + j] = (float)mi[j];
        }
    }
}

extern "C" void kernel_launch(void* const* d_in, const int* in_sizes, int n_in,
                              void* d_out, int out_size, void* d_ws, size_t ws_size,
                              hipStream_t stream) {
    const float* q = (const float*)d_in[0];   // [1, 128]
    const float* M = (const float*)d_in[1];   // [N, 128]
    const int N = in_sizes[1] / D;

    int nb = NBLOCKS;
    const size_t need = (size_t)nb * K * (sizeof(float) + sizeof(int));
    if (need > ws_size) nb = (int)(ws_size / (K * (sizeof(float) + sizeof(int))));

    float* cand_v = (float*)d_ws;
    int*   cand_i = (int*)((char*)d_ws + (size_t)nb * K * sizeof(float));

    hipLaunchKernelGGL(cossim_topk_pass1, dim3(nb), dim3(BLOCK), 0, stream,
                       q, M, N, cand_v, cand_i);
    hipLaunchKernelGGL(cossim_topk_pass2, dim3(1), dim3(64), 0, stream,
                       cand_v, cand_i, nb * K, (float*)d_out);
}

// Round 2
// 215.004 us; speedup vs baseline: 1.2775x; 1.2775x over previous
//
#include <hip/hip_runtime.h>

#define K 5
#define D 128
#define BLOCK 256
#define NBLOCKS 2048
#define UNROLL 4

// Insert (sim, idx) into a descending-sorted top-K list held in registers.
__device__ __forceinline__ void insert_top(float sim, int idx, float bv[K], int bi[K]) {
    if (sim > bv[K - 1]) {
        bv[K - 1] = sim;
        bi[K - 1] = idx;
#pragma unroll
        for (int j = K - 1; j > 0; --j) {
            if (bv[j] > bv[j - 1]) {
                float tv = bv[j]; bv[j] = bv[j - 1]; bv[j - 1] = tv;
                int   ti = bi[j]; bi[j] = bi[j - 1]; bi[j - 1] = ti;
            }
        }
    }
}

// Pass 1: each 32-lane group computes cosine sim for its rows, 4 rows per
// iteration (4 independent 1-KiB wave-loads in flight -> MLP to cover HBM
// latency). Block merges its 8 group-lists -> 5 candidates/block.
extern "C" __global__ void __launch_bounds__(BLOCK)
cossim_topk_pass1(const float* __restrict__ q, const float* __restrict__ M, int N,
                  float* __restrict__ cand_v, int* __restrict__ cand_i) {
    const int tid  = threadIdx.x;
    const int l    = tid & 31;                 // lane within 32-group
    const int gpb  = blockDim.x >> 5;          // groups per block (8)
    const int gid  = blockIdx.x * gpb + (tid >> 5);
    const int ngrp = gridDim.x * gpb;

    // Each lane holds 4 consecutive q elements (32 lanes * 4 = 128 = D).
    const float4 qv = reinterpret_cast<const float4*>(q)[l];

    // ||q|| via butterfly reduce within the 32-lane group.
    float q2 = qv.x * qv.x + qv.y * qv.y + qv.z * qv.z + qv.w * qv.w;
#pragma unroll
    for (int m = 16; m >= 1; m >>= 1) q2 += __shfl_xor(q2, m);
    const float qn = sqrtf(q2);

    float bv[K]; int bi[K];
#pragma unroll
    for (int j = 0; j < K; ++j) { bv[j] = -3.0e38f; bi[j] = 0; }

    int row = gid * UNROLL;
    const int stride = ngrp * UNROLL;
    for (; row + UNROLL <= N; row += stride) {
        float4 v[UNROLL];
#pragma unroll
        for (int u = 0; u < UNROLL; ++u)
            v[u] = reinterpret_cast<const float4*>(M + (size_t)(row + u) * D)[l];
#pragma unroll
        for (int u = 0; u < UNROLL; ++u) {
            float dot = fmaf(v[u].x, qv.x, fmaf(v[u].y, qv.y, fmaf(v[u].z, qv.z, v[u].w * qv.w)));
            float ss  = fmaf(v[u].x, v[u].x,  fmaf(v[u].y, v[u].y,  fmaf(v[u].z, v[u].z,  v[u].w * v[u].w)));
#pragma unroll
            for (int m = 16; m >= 1; m >>= 1) {
                dot += __shfl_xor(dot, m);
                ss  += __shfl_xor(ss, m);
            }
            const float sim = dot / fmaxf(qn * sqrtf(ss), 1e-8f);
            insert_top(sim, row + u, bv, bi);   // identical across the 32-group (no divergence)
        }
    }
    // Tail (only the straddling group, <UNROLL rows; N%4==0 -> usually empty).
    for (int r = row; r < N; ++r) {
        const float4 v = reinterpret_cast<const float4*>(M + (size_t)r * D)[l];
        float dot = fmaf(v.x, qv.x, fmaf(v.y, qv.y, fmaf(v.z, qv.z, v.w * qv.w)));
        float ss  = fmaf(v.x, v.x,  fmaf(v.y, v.y,  fmaf(v.z, v.z,  v.w * v.w)));
#pragma unroll
        for (int m = 16; m >= 1; m >>= 1) {
            dot += __shfl_xor(dot, m);
            ss  += __shfl_xor(ss, m);
        }
        const float sim = dot / fmaxf(qn * sqrtf(ss), 1e-8f);
        insert_top(sim, r, bv, bi);
    }

    // Merge the block's 8 group-lists.
    __shared__ float sv[(BLOCK / 32) * K];
    __shared__ int   si[(BLOCK / 32) * K];
    if (l == 0) {
        const int g = tid >> 5;
#pragma unroll
        for (int j = 0; j < K; ++j) { sv[g * K + j] = bv[j]; si[g * K + j] = bi[j]; }
    }
    __syncthreads();
    if (tid == 0) {
        float mv[K]; int mi[K];
#pragma unroll
        for (int j = 0; j < K; ++j) { mv[j] = sv[j]; mi[j] = si[j]; }
        for (int c = K; c < gpb * K; ++c) insert_top(sv[c], si[c], mv, mi);
#pragma unroll
        for (int j = 0; j < K; ++j) {
            cand_v[blockIdx.x * K + j] = mv[j];
            cand_i[blockIdx.x * K + j] = mi[j];
        }
    }
}

// Pass 2: one 256-thread block reduces NBLOCKS*K candidates to global top-K.
// Per-thread strided partial lists -> wave butterfly list-merge (6 steps) ->
// 4 wave leaders -> thread 0 final merge.
extern "C" __global__ void __launch_bounds__(256)
cossim_topk_pass2(const float* __restrict__ cand_v, const int* __restrict__ cand_i,
                  int ncand, float* __restrict__ out) {
    const int tid = threadIdx.x;
    float bv[K]; int bi[K];
#pragma unroll
    for (int j = 0; j < K; ++j) { bv[j] = -3.0e38f; bi[j] = 0; }

    for (int c = tid; c < ncand; c += 256) insert_top(cand_v[c], cand_i[c], bv, bi);

    // In-wave butterfly merge: after 6 steps every lane holds the wave's top-K.
#pragma unroll
    for (int m = 1; m <= 32; m <<= 1) {
        float ov[K]; int oi[K];
#pragma unroll
        for (int j = 0; j < K; ++j) { ov[j] = __shfl_xor(bv[j], m); oi[j] = __shfl_xor(bi[j], m); }
#pragma unroll
        for (int j = 0; j < K; ++j) insert_top(ov[j], oi[j], bv, bi);
    }

    __shared__ float sv[4 * K];
    __shared__ int   si[4 * K];
    if ((tid & 63) == 0) {
        const int w = tid >> 6;
#pragma unroll
        for (int j = 0; j < K; ++j) { sv[w * K + j] = bv[j]; si[w * K + j] = bi[j]; }
    }
    __syncthreads();

    if (tid == 0) {
        float mv[K]; int mi[K];
#pragma unroll
        for (int j = 0; j < K; ++j) { mv[j] = sv[j]; mi[j] = si[j]; }
        for (int c = K; c < 4 * K; ++c) insert_top(sv[c], si[c], mv, mi);
        // Output layout: [top_vals (K floats)] [top_idx (K, written as float)]
#pragma unroll
        for (int j = 0; j < K; ++j) {
            out[j]     = mv[j];
            out[K + j] = (float)mi[j];
        }
    }
}

extern "C" void kernel_launch(void* const* d_in, const int* in_sizes, int n_in,
                              void* d_out, int out_size, void* d_ws, size_t ws_size,
                              hipStream_t stream) {
    const float* q = (const float*)d_in[0];   // [1, 128]
    const float* M = (const float*)d_in[1];   // [N, 128]
    const int N = in_sizes[1] / D;

    int nb = NBLOCKS;
    const size_t need = (size_t)nb * K * (sizeof(float) + sizeof(int));
    if (need > ws_size) nb = (int)(ws_size / (K * (sizeof(float) + sizeof(int))));

    float* cand_v = (float*)d_ws;
    int*   cand_i = (int*)((char*)d_ws + (size_t)nb * K * sizeof(float));

    hipLaunchKernelGGL(cossim_topk_pass1, dim3(nb), dim3(BLOCK), 0, stream,
                       q, M, N, cand_v, cand_i);
    hipLaunchKernelGGL(cossim_topk_pass2, dim3(1), dim3(256), 0, stream,
                       cand_v, cand_i, nb * K, (float*)d_out);
}

// Round 3
// 206.220 us; speedup vs baseline: 1.3319x; 1.0426x over previous
//
#include <hip/hip_runtime.h>

#define K 5
#define D 128
#define BLOCK 256
#define NBLOCKS 2048

// Insert (sim, idx) into a descending-sorted top-K list held in registers.
__device__ __forceinline__ void insert_top(float sim, int idx, float bv[K], int bi[K]) {
    if (sim > bv[K - 1]) {
        bv[K - 1] = sim;
        bi[K - 1] = idx;
#pragma unroll
        for (int j = K - 1; j > 0; --j) {
            if (bv[j] > bv[j - 1]) {
                float tv = bv[j]; bv[j] = bv[j - 1]; bv[j - 1] = tv;
                int   ti = bi[j]; bi[j] = bi[j - 1]; bi[j - 1] = ti;
            }
        }
    }
}

// Pass 1: 8 lanes per row. Lane l owns row base+(l>>3), column chunk (l&7).
// One wave-iteration covers 8 rows (4 KiB) with 4 coalesced loads, 6 shuffles,
// and ONE sim/insert wave-instruction stream (8 distinct rows in parallel).
extern "C" __global__ void __launch_bounds__(BLOCK)
cossim_topk_pass1(const float* __restrict__ q, const float* __restrict__ M, int N,
                  float* __restrict__ cand_v, int* __restrict__ cand_i) {
    const int tid   = threadIdx.x;
    const int lane  = tid & 63;
    const int wib   = tid >> 6;                       // wave index in block (0..3)
    const int wid   = blockIdx.x * (BLOCK / 64) + wib; // global wave id
    const int nwave = gridDim.x * (BLOCK / 64);
    const int rsub  = lane >> 3;                      // row sub-index (0..7)
    const int chunk = lane & 7;                       // column chunk (0..7)

    const float4* __restrict__ Mf4 = reinterpret_cast<const float4*>(M);
    const float4* __restrict__ qf4 = reinterpret_cast<const float4*>(q);

    // Lane's q fragment: float4 indices {chunk, chunk+8, chunk+16, chunk+24}.
    float4 qf[4];
#pragma unroll
    for (int j = 0; j < 4; ++j) qf[j] = qf4[chunk + j * 8];

    // ||q||^2: per-lane partial, reduced over the 8-lane group (xor 1,2,4).
    float q2 = 0.f;
#pragma unroll
    for (int j = 0; j < 4; ++j)
        q2 = fmaf(qf[j].x, qf[j].x, fmaf(qf[j].y, qf[j].y,
             fmaf(qf[j].z, qf[j].z, fmaf(qf[j].w, qf[j].w, q2))));
#pragma unroll
    for (int m = 1; m <= 4; m <<= 1) q2 += __shfl_xor(q2, m);
    const float qn = sqrtf(q2);

    float bv[K]; int bi[K];
#pragma unroll
    for (int j = 0; j < K; ++j) { bv[j] = -3.0e38f; bi[j] = 0; }

    const int stride = nwave * 8;
    for (int base = wid * 8; base < N; base += stride) {
        const int row   = base + rsub;
        const int rowc  = row < N ? row : N - 1;
        const size_t rb = (size_t)rowc * (D / 4);     // row base in float4s

        float4 v[4];
#pragma unroll
        for (int j = 0; j < 4; ++j) v[j] = Mf4[rb + chunk + j * 8];

        float dot = 0.f, ss = 0.f;
#pragma unroll
        for (int j = 0; j < 4; ++j) {
            dot = fmaf(v[j].x, qf[j].x, fmaf(v[j].y, qf[j].y,
                  fmaf(v[j].z, qf[j].z, fmaf(v[j].w, qf[j].w, dot))));
            ss  = fmaf(v[j].x, v[j].x,  fmaf(v[j].y, v[j].y,
                  fmaf(v[j].z, v[j].z,  fmaf(v[j].w, v[j].w, ss))));
        }
        // Reduce within the 8-lane row group (one instr covers all 8 rows).
#pragma unroll
        for (int m = 1; m <= 4; m <<= 1) {
            dot += __shfl_xor(dot, m);
            ss  += __shfl_xor(ss, m);
        }
        const float sim = dot / fmaxf(qn * sqrtf(ss), 1e-8f);
        if (row < N) insert_top(sim, row, bv, bi);
    }

    // Cross-group merge within the wave: lists identical inside each 8-lane
    // group; merge across groups via xor 8,16,32 butterfly of K-lists.
#pragma unroll
    for (int m = 8; m <= 32; m <<= 1) {
        float ov[K]; int oi[K];
#pragma unroll
        for (int j = 0; j < K; ++j) { ov[j] = __shfl_xor(bv[j], m); oi[j] = __shfl_xor(bi[j], m); }
#pragma unroll
        for (int j = 0; j < K; ++j) insert_top(ov[j], oi[j], bv, bi);
    }

    // Merge the block's 4 wave-lists via LDS.
    __shared__ float sv[(BLOCK / 64) * K];
    __shared__ int   si[(BLOCK / 64) * K];
    if (lane == 0) {
#pragma unroll
        for (int j = 0; j < K; ++j) { sv[wib * K + j] = bv[j]; si[wib * K + j] = bi[j]; }
    }
    __syncthreads();
    if (tid == 0) {
        float mv[K]; int mi[K];
#pragma unroll
        for (int j = 0; j < K; ++j) { mv[j] = sv[j]; mi[j] = si[j]; }
        for (int c = K; c < (BLOCK / 64) * K; ++c) insert_top(sv[c], si[c], mv, mi);
#pragma unroll
        for (int j = 0; j < K; ++j) {
            cand_v[blockIdx.x * K + j] = mv[j];
            cand_i[blockIdx.x * K + j] = mi[j];
        }
    }
}

// Pass 2: one 256-thread block reduces NBLOCKS*K candidates to global top-K.
extern "C" __global__ void __launch_bounds__(256)
cossim_topk_pass2(const float* __restrict__ cand_v, const int* __restrict__ cand_i,
                  int ncand, float* __restrict__ out) {
    const int tid = threadIdx.x;
    float bv[K]; int bi[K];
#pragma unroll
    for (int j = 0; j < K; ++j) { bv[j] = -3.0e38f; bi[j] = 0; }

    for (int c = tid; c < ncand; c += 256) insert_top(cand_v[c], cand_i[c], bv, bi);

    // In-wave butterfly merge: after 6 steps every lane holds the wave's top-K.
#pragma unroll
    for (int m = 1; m <= 32; m <<= 1) {
        float ov[K]; int oi[K];
#pragma unroll
        for (int j = 0; j < K; ++j) { ov[j] = __shfl_xor(bv[j], m); oi[j] = __shfl_xor(bi[j], m); }
#pragma unroll
        for (int j = 0; j < K; ++j) insert_top(ov[j], oi[j], bv, bi);
    }

    __shared__ float sv[4 * K];
    __shared__ int   si[4 * K];
    if ((tid & 63) == 0) {
        const int w = tid >> 6;
#pragma unroll
        for (int j = 0; j < K; ++j) { sv[w * K + j] = bv[j]; si[w * K + j] = bi[j]; }
    }
    __syncthreads();

    if (tid == 0) {
        float mv[K]; int mi[K];
#pragma unroll
        for (int j = 0; j < K; ++j) { mv[j] = sv[j]; mi[j] = si[j]; }
        for (int c = K; c < 4 * K; ++c) insert_top(sv[c], si[c], mv, mi);
        // Output layout: [top_vals (K floats)] [top_idx (K, written as float)]
#pragma unroll
        for (int j = 0; j < K; ++j) {
            out[j]     = mv[j];
            out[K + j] = (float)mi[j];
        }
    }
}

extern "C" void kernel_launch(void* const* d_in, const int* in_sizes, int n_in,
                              void* d_out, int out_size, void* d_ws, size_t ws_size,
                              hipStream_t stream) {
    const float* q = (const float*)d_in[0];   // [1, 128]
    const float* M = (const float*)d_in[1];   // [N, 128]
    const int N = in_sizes[1] / D;

    int nb = NBLOCKS;
    const size_t need = (size_t)nb * K * (sizeof(float) + sizeof(int));
    if (need > ws_size) nb = (int)(ws_size / (K * (sizeof(float) + sizeof(int))));

    float* cand_v = (float*)d_ws;
    int*   cand_i = (int*)((char*)d_ws + (size_t)nb * K * sizeof(float));

    hipLaunchKernelGGL(cossim_topk_pass1, dim3(nb), dim3(BLOCK), 0, stream,
                       q, M, N, cand_v, cand_i);
    hipLaunchKernelGGL(cossim_topk_pass2, dim3(1), dim3(256), 0, stream,
                       cand_v, cand_i, nb * K, (float*)d_out);
}

// Round 4
// 184.734 us; speedup vs baseline: 1.4868x; 1.1163x over previous
//
#include <hip/hip_runtime.h>

#define K 5
#define D 128
#define BLOCK 256
#define NBLOCKS 2048

typedef float vf4 __attribute__((ext_vector_type(4)));

// Insert (sim, idx) into a descending-sorted top-K list held in registers.
__device__ __forceinline__ void insert_top(float sim, int idx, float bv[K], int bi[K]) {
    if (sim > bv[K - 1]) {
        bv[K - 1] = sim;
        bi[K - 1] = idx;
#pragma unroll
        for (int j = K - 1; j > 0; --j) {
            if (bv[j] > bv[j - 1]) {
                float tv = bv[j]; bv[j] = bv[j - 1]; bv[j - 1] = tv;
                int   ti = bi[j]; bi[j] = bi[j - 1]; bi[j - 1] = ti;
            }
        }
    }
}

// Pass 1: 8 lanes per row, 16 rows (8 KiB) per wave-iteration, 2-deep pipeline:
// all 8 nontemporal loads issued up front, then the two 8-row halves computed
// back-to-back so the second half's loads stay in flight under the first
// half's shuffle/sqrt/div chain.
extern "C" __global__ void __launch_bounds__(BLOCK)
cossim_topk_pass1(const float* __restrict__ q, const float* __restrict__ M, int N,
                  float* __restrict__ cand_v, int* __restrict__ cand_i) {
    const int tid   = threadIdx.x;
    const int lane  = tid & 63;
    const int wib   = tid >> 6;                        // wave index in block (0..3)
    const int wid   = blockIdx.x * (BLOCK / 64) + wib; // global wave id
    const int nwave = gridDim.x * (BLOCK / 64);
    const int rsub  = lane >> 3;                       // row sub-index (0..7)
    const int chunk = lane & 7;                        // column chunk (0..7)

    const vf4* __restrict__ Mv = reinterpret_cast<const vf4*>(M);
    const float4* __restrict__ qf4 = reinterpret_cast<const float4*>(q);

    // Lane's q fragment: float4 indices {chunk, chunk+8, chunk+16, chunk+24}.
    float4 qf[4];
#pragma unroll
    for (int j = 0; j < 4; ++j) qf[j] = qf4[chunk + j * 8];

    // ||q||^2: per-lane partial, reduced over the 8-lane group (xor 1,2,4).
    float q2 = 0.f;
#pragma unroll
    for (int j = 0; j < 4; ++j)
        q2 = fmaf(qf[j].x, qf[j].x, fmaf(qf[j].y, qf[j].y,
             fmaf(qf[j].z, qf[j].z, fmaf(qf[j].w, qf[j].w, q2))));
#pragma unroll
    for (int m = 1; m <= 4; m <<= 1) q2 += __shfl_xor(q2, m);
    const float qn = sqrtf(q2);

    float bv[K]; int bi[K];
#pragma unroll
    for (int j = 0; j < K; ++j) { bv[j] = -3.0e38f; bi[j] = 0; }

    const int stride = nwave * 16;
    for (int base = wid * 16; base < N; base += stride) {
        const int rowA = base + rsub;
        const int rowB = base + 8 + rsub;
        const int rcA  = rowA < N ? rowA : N - 1;
        const int rcB  = rowB < N ? rowB : N - 1;
        const size_t rbA = (size_t)rcA * (D / 4);
        const size_t rbB = (size_t)rcB * (D / 4);

        // Issue all 8 nontemporal loads (8 KiB/wave in flight).
        vf4 a[4], b[4];
#pragma unroll
        for (int j = 0; j < 4; ++j) a[j] = __builtin_nontemporal_load(&Mv[rbA + chunk + j * 8]);
#pragma unroll
        for (int j = 0; j < 4; ++j) b[j] = __builtin_nontemporal_load(&Mv[rbB + chunk + j * 8]);

        // Half A
        {
            float dot = 0.f, ss = 0.f;
#pragma unroll
            for (int j = 0; j < 4; ++j) {
                dot = fmaf(a[j].x, qf[j].x, fmaf(a[j].y, qf[j].y,
                      fmaf(a[j].z, qf[j].z, fmaf(a[j].w, qf[j].w, dot))));
                ss  = fmaf(a[j].x, a[j].x,  fmaf(a[j].y, a[j].y,
                      fmaf(a[j].z, a[j].z,  fmaf(a[j].w, a[j].w, ss))));
            }
#pragma unroll
            for (int m = 1; m <= 4; m <<= 1) { dot += __shfl_xor(dot, m); ss += __shfl_xor(ss, m); }
            const float sim = dot / fmaxf(qn * sqrtf(ss), 1e-8f);
            if (rowA < N) insert_top(sim, rowA, bv, bi);
        }
        // Half B
        {
            float dot = 0.f, ss = 0.f;
#pragma unroll
            for (int j = 0; j < 4; ++j) {
                dot = fmaf(b[j].x, qf[j].x, fmaf(b[j].y, qf[j].y,
                      fmaf(b[j].z, qf[j].z, fmaf(b[j].w, qf[j].w, dot))));
                ss  = fmaf(b[j].x, b[j].x,  fmaf(b[j].y, b[j].y,
                      fmaf(b[j].z, b[j].z,  fmaf(b[j].w, b[j].w, ss))));
            }
#pragma unroll
            for (int m = 1; m <= 4; m <<= 1) { dot += __shfl_xor(dot, m); ss += __shfl_xor(ss, m); }
            const float sim = dot / fmaxf(qn * sqrtf(ss), 1e-8f);
            if (rowB < N) insert_top(sim, rowB, bv, bi);
        }
    }

    // Cross-group merge within the wave: lists identical inside each 8-lane
    // group; merge across groups via xor 8,16,32 butterfly of K-lists.
#pragma unroll
    for (int m = 8; m <= 32; m <<= 1) {
        float ov[K]; int oi[K];
#pragma unroll
        for (int j = 0; j < K; ++j) { ov[j] = __shfl_xor(bv[j], m); oi[j] = __shfl_xor(bi[j], m); }
#pragma unroll
        for (int j = 0; j < K; ++j) insert_top(ov[j], oi[j], bv, bi);
    }

    // Merge the block's 4 wave-lists via LDS.
    __shared__ float sv[(BLOCK / 64) * K];
    __shared__ int   si[(BLOCK / 64) * K];
    if (lane == 0) {
#pragma unroll
        for (int j = 0; j < K; ++j) { sv[wib * K + j] = bv[j]; si[wib * K + j] = bi[j]; }
    }
    __syncthreads();
    if (tid == 0) {
        float mv[K]; int mi[K];
#pragma unroll
        for (int j = 0; j < K; ++j) { mv[j] = sv[j]; mi[j] = si[j]; }
        for (int c = K; c < (BLOCK / 64) * K; ++c) insert_top(sv[c], si[c], mv, mi);
#pragma unroll
        for (int j = 0; j < K; ++j) {
            cand_v[blockIdx.x * K + j] = mv[j];
            cand_i[blockIdx.x * K + j] = mi[j];
        }
    }
}

// Pass 2: one 256-thread block reduces NBLOCKS*K candidates to global top-K.
extern "C" __global__ void __launch_bounds__(256)
cossim_topk_pass2(const float* __restrict__ cand_v, const int* __restrict__ cand_i,
                  int ncand, float* __restrict__ out) {
    const int tid = threadIdx.x;
    float bv[K]; int bi[K];
#pragma unroll
    for (int j = 0; j < K; ++j) { bv[j] = -3.0e38f; bi[j] = 0; }

    for (int c = tid; c < ncand; c += 256) insert_top(cand_v[c], cand_i[c], bv, bi);

    // In-wave butterfly merge: after 6 steps every lane holds the wave's top-K.
#pragma unroll
    for (int m = 1; m <= 32; m <<= 1) {
        float ov[K]; int oi[K];
#pragma unroll
        for (int j = 0; j < K; ++j) { ov[j] = __shfl_xor(bv[j], m); oi[j] = __shfl_xor(bi[j], m); }
#pragma unroll
        for (int j = 0; j < K; ++j) insert_top(ov[j], oi[j], bv, bi);
    }

    __shared__ float sv[4 * K];
    __shared__ int   si[4 * K];
    if ((tid & 63) == 0) {
        const int w = tid >> 6;
#pragma unroll
        for (int j = 0; j < K; ++j) { sv[w * K + j] = bv[j]; si[w * K + j] = bi[j]; }
    }
    __syncthreads();

    if (tid == 0) {
        float mv[K]; int mi[K];
#pragma unroll
        for (int j = 0; j < K; ++j) { mv[j] = sv[j]; mi[j] = si[j]; }
        for (int c = K; c < 4 * K; ++c) insert_top(sv[c], si[c], mv, mi);
        // Output layout: [top_vals (K floats)] [top_idx (K, written as float)]
#pragma unroll
        for (int j = 0; j < K; ++j) {
            out[j]     = mv[j];
            out[K + j] = (float)mi[j];
        }
    }
}

extern "C" void kernel_launch(void* const* d_in, const int* in_sizes, int n_in,
                              void* d_out, int out_size, void* d_ws, size_t ws_size,
                              hipStream_t stream) {
    const float* q = (const float*)d_in[0];   // [1, 128]
    const float* M = (const float*)d_in[1];   // [N, 128]
    const int N = in_sizes[1] / D;

    int nb = NBLOCKS;
    const size_t need = (size_t)nb * K * (sizeof(float) + sizeof(int));
    if (need > ws_size) nb = (int)(ws_size / (K * (sizeof(float) + sizeof(int))));

    float* cand_v = (float*)d_ws;
    int*   cand_i = (int*)((char*)d_ws + (size_t)nb * K * sizeof(float));

    hipLaunchKernelGGL(cossim_topk_pass1, dim3(nb), dim3(BLOCK), 0, stream,
                       q, M, N, cand_v, cand_i);
    hipLaunchKernelGGL(cossim_topk_pass2, dim3(1), dim3(256), 0, stream,
                       cand_v, cand_i, nb * K, (float*)d_out);
}